// Round 3
// baseline (791.442 us; speedup 1.0000x reference)
//
#include <hip/hip_runtime.h>

#define NNODES 50000
#define NEDGES 800000
#define NGRAPH 500
#define CH 100
#define CIN0 33
#define BN_EPS 1e-5f

#define SCAN_TPB 256
#define SCAN_IPT 4
#define SCAN_TILE (SCAN_TPB * SCAN_IPT)
#define SCAN_BLOCKS ((NNODES + SCAN_TILE - 1) / SCAN_TILE)

// ---------------- init: zero histogram counters + BN stat accumulators ----------------
__global__ void k_init(int* __restrict__ cnt, float* __restrict__ stats) {
    int i = blockIdx.x * blockDim.x + threadIdx.x;
    if (i < NNODES) cnt[i] = 0;
    if (i < 1024) stats[i] = 0.f;
}

// ---------------- in-degree histogram over dst ----------------
__global__ void k_hist(const int* __restrict__ dst, int* __restrict__ cnt) {
    int e = blockIdx.x * blockDim.x + threadIdx.x;
    if (e < NEDGES) atomicAdd(&cnt[dst[e]], 1);
}

// ---------------- dinv = rsqrt(deg), deg = cnt + 1 (self loop) ----------------
__global__ void k_dinv(const int* __restrict__ cnt, float* __restrict__ dinv) {
    int i = blockIdx.x * blockDim.x + threadIdx.x;
    if (i < NNODES) dinv[i] = rsqrtf((float)(cnt[i] + 1));
}

// ---------------- exclusive scan of cnt -> rowptr (3 kernels) ----------------
__global__ void k_scan1(const int* __restrict__ cnt, int* __restrict__ rowptr,
                        int* __restrict__ blkSums) {
    __shared__ int ts[SCAN_TPB];
    int tid = threadIdx.x;
    int base = blockIdx.x * SCAN_TILE + tid * SCAN_IPT;
    int v[SCAN_IPT];
    int s = 0;
    #pragma unroll
    for (int j = 0; j < SCAN_IPT; ++j) {
        int i = base + j;
        v[j] = (i < NNODES) ? cnt[i] : 0;
        s += v[j];
    }
    ts[tid] = s;
    __syncthreads();
    for (int off = 1; off < SCAN_TPB; off <<= 1) {
        int add = (tid >= off) ? ts[tid - off] : 0;
        __syncthreads();
        ts[tid] += add;
        __syncthreads();
    }
    int run = ts[tid] - s;  // exclusive prefix within block
    #pragma unroll
    for (int j = 0; j < SCAN_IPT; ++j) {
        int i = base + j;
        if (i < NNODES) rowptr[i] = run;
        run += v[j];
    }
    if (tid == SCAN_TPB - 1) blkSums[blockIdx.x] = ts[tid];
}

__global__ void k_scan2(const int* __restrict__ blkSums, int* __restrict__ blkOff) {
    if (threadIdx.x == 0) {
        int run = 0;
        for (int i = 0; i < SCAN_BLOCKS; ++i) { blkOff[i] = run; run += blkSums[i]; }
    }
}

__global__ void k_scan3(int* __restrict__ rowptr, int* __restrict__ cursor,
                        const int* __restrict__ blkOff) {
    int off = blkOff[blockIdx.x];
    int base = blockIdx.x * SCAN_TILE + threadIdx.x * SCAN_IPT;
    #pragma unroll
    for (int j = 0; j < SCAN_IPT; ++j) {
        int i = base + j;
        if (i < NNODES) {
            int vv = rowptr[i] + off;
            rowptr[i] = vv;
            cursor[i] = vv;
        }
    }
    if (blockIdx.x == 0 && threadIdx.x == 0) rowptr[NNODES] = NEDGES;
}

// ---------------- scatter edges into CSR (by dst); pack (src, dinv[src]) ----------------
__global__ void k_scatter(const int* __restrict__ src, const int* __restrict__ dst,
                          const float* __restrict__ dinv, int* __restrict__ cursor,
                          int2* __restrict__ ew) {
    int e = blockIdx.x * blockDim.x + threadIdx.x;
    if (e < NEDGES) {
        int d = dst[e], s = src[e];
        int pos = atomicAdd(&cursor[d], 1);
        ew[pos] = make_int2(s, __float_as_int(dinv[s]));
    }
}

// ---------------- aggregate with optional fused BN(+ReLU) on gathered rows ----------------
// a[i] = dinv[i]*( sum_e dinv[src]*f(h[src]) + dinv[i]*f(h[i]) ),
// f(v) = BN ? relu(v*scale+shift) : v. One wave per node; 64 edge descriptors
// loaded coalesced and broadcast via readlane/shfl; row gathers unrolled 8x.
template<int C, bool BN>
__global__ __launch_bounds__(256) void k_aggregate(
    const float* __restrict__ h, float* __restrict__ a, const int* __restrict__ rowptr,
    const int2* __restrict__ ew, const float* __restrict__ dinv,
    const float* __restrict__ sst) {
    int node = (blockIdx.x * 256 + threadIdx.x) >> 6;
    int lane = threadIdx.x & 63;
    if (node >= NNODES) return;
    int p0 = rowptr[node], p1 = rowptr[node + 1];
    float di = dinv[node];

    if constexpr ((C & 1) == 0) {
        constexpr int HALF = C / 2;            // 50 for C=100
        bool act = lane < HALF;
        float scx = 0.f, scy = 0.f, shx = 0.f, shy = 0.f;
        if (BN && act) {
            float2 sc2 = ((const float2*)sst)[lane];
            float2 sh2 = ((const float2*)(sst + 128))[lane];
            scx = sc2.x; scy = sc2.y; shx = sh2.x; shy = sh2.y;
        }
        float ax = 0.f, ay = 0.f;
        for (int base = p0; base < p1; base += 64) {
            int nn = p1 - base; if (nn > 64) nn = 64;
            int2 e = make_int2(0, 0);
            if (lane < nn) e = ew[base + lane];
            int myc = e.x; float myw = __int_as_float(e.y);
            int j = 0;
            for (; j + 8 <= nn; j += 8) {
                int s[8]; float w[8];
                #pragma unroll
                for (int t = 0; t < 8; ++t) { s[t] = __shfl(myc, j + t); w[t] = __shfl(myw, j + t); }
                if (act) {
                    float2 v[8];
                    #pragma unroll
                    for (int t = 0; t < 8; ++t) v[t] = ((const float2*)(h + (size_t)s[t] * C))[lane];
                    #pragma unroll
                    for (int t = 0; t < 8; ++t) {
                        float vx = v[t].x, vy = v[t].y;
                        if (BN) {
                            vx = fmaxf(vx * scx + shx, 0.f);
                            vy = fmaxf(vy * scy + shy, 0.f);
                        }
                        ax += w[t] * vx; ay += w[t] * vy;
                    }
                }
            }
            for (; j < nn; ++j) {
                int s0 = __shfl(myc, j);
                float w0 = __shfl(myw, j);
                if (act) {
                    float2 v = ((const float2*)(h + (size_t)s0 * C))[lane];
                    float vx = v.x, vy = v.y;
                    if (BN) {
                        vx = fmaxf(vx * scx + shx, 0.f);
                        vy = fmaxf(vy * scy + shy, 0.f);
                    }
                    ax += w0 * vx; ay += w0 * vy;
                }
            }
        }
        if (act) {
            float2 hv = ((const float2*)(h + (size_t)node * C))[lane];
            float hx = hv.x, hy = hv.y;
            if (BN) {
                hx = fmaxf(hx * scx + shx, 0.f);
                hy = fmaxf(hy * scy + shy, 0.f);
            }
            float2 o;
            o.x = di * (ax + di * hx);
            o.y = di * (ay + di * hy);
            ((float2*)(a + (size_t)node * C))[lane] = o;
        }
    } else {
        bool m0 = lane < C;
        float sc = 0.f, sh = 0.f;
        if (BN && m0) { sc = sst[lane]; sh = sst[128 + lane]; }
        float acc0 = 0.f;
        for (int base = p0; base < p1; base += 64) {
            int nn = p1 - base; if (nn > 64) nn = 64;
            int2 e = make_int2(0, 0);
            if (lane < nn) e = ew[base + lane];
            int myc = e.x; float myw = __int_as_float(e.y);
            int j = 0;
            for (; j + 8 <= nn; j += 8) {
                int s[8]; float w[8];
                #pragma unroll
                for (int t = 0; t < 8; ++t) { s[t] = __shfl(myc, j + t); w[t] = __shfl(myw, j + t); }
                if (m0) {
                    float v[8];
                    #pragma unroll
                    for (int t = 0; t < 8; ++t) v[t] = h[(size_t)s[t] * C + lane];
                    #pragma unroll
                    for (int t = 0; t < 8; ++t) {
                        float vv = v[t];
                        if (BN) vv = fmaxf(vv * sc + sh, 0.f);
                        acc0 += w[t] * vv;
                    }
                }
            }
            for (; j < nn; ++j) {
                int s0 = __shfl(myc, j);
                float w0 = __shfl(myw, j);
                if (m0) {
                    float vv = h[(size_t)s0 * C + lane];
                    if (BN) vv = fmaxf(vv * sc + sh, 0.f);
                    acc0 += w0 * vv;
                }
            }
        }
        if (m0) {
            float hv = h[(size_t)node * C + lane];
            if (BN) hv = fmaxf(hv * sc + sh, 0.f);
            a[(size_t)node * C + lane] = di * (acc0 + di * hv);
        }
    }
}

// ---------------- Z = A @ W + bias ; fused per-channel sum/sumsq partials ----------------
// 64 rows x 100 cols per block; k chunked by 20 (LDS ~14 KB -> high occupancy).
// 200 threads: thread owns rows {rt, rt+8, ..., rt+56} (interleaved -> aS reads hit
// distinct banks: 20*rt mod 32 all distinct) and cols c0..c0+3.
template<int K, int CP>  // CP = K padded to multiple of 20
__global__ __launch_bounds__(256) void k_gemm(
    const float* __restrict__ A, const float* __restrict__ W, const float* __restrict__ bias,
    float* __restrict__ Z, float* __restrict__ gsum, float* __restrict__ gsq) {
    __shared__ __align__(16) float wS[20 * CH];   // 8 KB
    __shared__ __align__(16) float aS[64 * 20];   // 5 KB
    __shared__ float sSum[CH], sSq[CH];
    int tid = threadIdx.x;
    for (int i = tid; i < CH; i += 256) { sSum[i] = 0.f; sSq[i] = 0.f; }
    int row0 = blockIdx.x * 64;
    int ct = tid % 25, rt = tid / 25;  // ct 0..24, rt 0..7 (for tid<200)
    int c0 = ct * 4;
    float acc[8][4] = {};

    for (int kc0 = 0; kc0 < CP; kc0 += 20) {
        // stage W chunk [20][CH]
        for (int i = tid; i < 20 * CH; i += 256) {
            int kk = i / CH, c = i % CH;
            int k = kc0 + kk;
            wS[i] = (k < K) ? W[k * CH + c] : 0.f;
        }
        // stage A chunk [64][20]
        for (int i = tid; i < 64 * 20; i += 256) {
            int r = i / 20, kk = i % 20;
            int k = kc0 + kk;
            int row = row0 + r;
            aS[i] = (row < NNODES && k < K) ? A[(size_t)row * K + k] : 0.f;
        }
        __syncthreads();
        if (tid < 200) {
            #pragma unroll
            for (int kk = 0; kk < 20; kk += 4) {
                float4 w0 = *(const float4*)&wS[kk * CH + c0];
                float4 w1 = *(const float4*)&wS[(kk + 1) * CH + c0];
                float4 w2 = *(const float4*)&wS[(kk + 2) * CH + c0];
                float4 w3 = *(const float4*)&wS[(kk + 3) * CH + c0];
                #pragma unroll
                for (int j = 0; j < 8; ++j) {
                    int r = rt + 8 * j;
                    float4 av = *(const float4*)&aS[r * 20 + kk];
                    acc[j][0] += av.x * w0.x + av.y * w1.x + av.z * w2.x + av.w * w3.x;
                    acc[j][1] += av.x * w0.y + av.y * w1.y + av.z * w2.y + av.w * w3.y;
                    acc[j][2] += av.x * w0.z + av.y * w1.z + av.z * w2.z + av.w * w3.z;
                    acc[j][3] += av.x * w0.w + av.y * w1.w + av.z * w2.w + av.w * w3.w;
                }
            }
        }
        __syncthreads();
    }

    if (tid < 200) {
        float b0 = bias[c0], b1 = bias[c0 + 1], b2 = bias[c0 + 2], b3 = bias[c0 + 3];
        float cs0 = 0, cs1 = 0, cs2 = 0, cs3 = 0, cq0 = 0, cq1 = 0, cq2 = 0, cq3 = 0;
        #pragma unroll
        for (int j = 0; j < 8; ++j) {
            int r = row0 + rt + 8 * j;
            if (r < NNODES) {
                float z0 = acc[j][0] + b0, z1 = acc[j][1] + b1;
                float z2 = acc[j][2] + b2, z3 = acc[j][3] + b3;
                *reinterpret_cast<float4*>(&Z[(size_t)r * CH + c0]) = make_float4(z0, z1, z2, z3);
                cs0 += z0; cs1 += z1; cs2 += z2; cs3 += z3;
                cq0 += z0 * z0; cq1 += z1 * z1; cq2 += z2 * z2; cq3 += z3 * z3;
            }
        }
        atomicAdd(&sSum[c0], cs0); atomicAdd(&sSum[c0 + 1], cs1);
        atomicAdd(&sSum[c0 + 2], cs2); atomicAdd(&sSum[c0 + 3], cs3);
        atomicAdd(&sSq[c0], cq0); atomicAdd(&sSq[c0 + 1], cq1);
        atomicAdd(&sSq[c0 + 2], cq2); atomicAdd(&sSq[c0 + 3], cq3);
    }
    __syncthreads();
    if (tid < CH) { atomicAdd(&gsum[tid], sSum[tid]); atomicAdd(&gsq[tid], sSq[tid]); }
}

// ---------------- BN finalize: scale/shift per channel ----------------
__global__ void k_finalize(const float* __restrict__ gsum, const float* __restrict__ gsq,
                           const float* __restrict__ gamma, const float* __restrict__ beta,
                           float* __restrict__ sst) {
    int c = threadIdx.x;
    if (c < CH) {
        float mean = gsum[c] * (1.f / NNODES);
        float var = gsq[c] * (1.f / NNODES) - mean * mean;
        float sc = gamma[c] * rsqrtf(var + BN_EPS);
        sst[c] = sc;
        sst[128 + c] = beta[c] - mean * sc;
    }
}

// ---------------- global_add_pool of BN(z) (no relu) via binary search ----------------
__global__ void k_pool(const float* __restrict__ Zl, const int* __restrict__ batch,
                       const float* __restrict__ sst, float* __restrict__ g) {
    int gid = blockIdx.x;
    int lo = 0, hi = NNODES;
    while (lo < hi) { int mid = (lo + hi) >> 1; if (batch[mid] < gid) lo = mid + 1; else hi = mid; }
    int start = lo;
    hi = NNODES;
    while (lo < hi) { int mid = (lo + hi) >> 1; if (batch[mid] < gid + 1) lo = mid + 1; else hi = mid; }
    int end = lo;
    int c = threadIdx.x;
    if (c >= CH) return;
    float sc = sst[c], sh = sst[128 + c];
    float acc = 0.f;
    for (int r = start; r < end; ++r) acc += Zl[(size_t)r * CH + c];
    g[gid * CH + c] = acc * sc + (float)(end - start) * sh;
}

// ---------------- out = leakyrelu(g @ Wout + bout, 0.1) ----------------
__global__ __launch_bounds__(256) void k_out(const float* __restrict__ g,
                                             const float* __restrict__ Wout,
                                             const float* __restrict__ bout,
                                             float* __restrict__ out) {
    __shared__ float gS[CH];
    int gid = blockIdx.x, tid = threadIdx.x;
    if (tid < CH) gS[tid] = g[gid * CH + tid];
    __syncthreads();
    if (tid >= 200) return;
    float acc = bout[tid];
    for (int k = 0; k < CH; ++k) acc += gS[k] * Wout[k * 200 + tid];
    out[gid * 200 + tid] = acc > 0.f ? acc : 0.1f * acc;
}

extern "C" void kernel_launch(void* const* d_in, const int* in_sizes, int n_in,
                              void* d_out, int out_size, void* d_ws, size_t ws_size,
                              hipStream_t stream) {
    const float* x = (const float*)d_in[0];
    const int* ei = (const int*)d_in[1];
    const int* batch = (const int*)d_in[2];
    const float* W0 = (const float*)d_in[3];
    const float* Wrest = (const float*)d_in[4];
    const float* b = (const float*)d_in[5];
    const float* gamma = (const float*)d_in[6];
    const float* beta = (const float*)d_in[7];
    const float* Wout = (const float*)d_in[8];
    const float* bout = (const float*)d_in[9];
    float* out = (float*)d_out;
    const int* srcA = ei;
    const int* dstA = ei + NEDGES;

    char* wsb = (char*)d_ws;
    size_t off = 0;
    auto alloc = [&](size_t elems) -> void* {
        void* p = (void*)(wsb + off);
        off += ((elems + 7) & ~(size_t)7) * 4;
        return p;
    };
    int* cnt = (int*)alloc(NNODES);
    int* rowptr = (int*)alloc(NNODES + 1);
    int* cursor = (int*)alloc(NNODES);
    float* dinv = (float*)alloc(NNODES);
    int* scanBlk = (int*)alloc(64);
    int* scanOff = (int*)alloc(64);
    float* stats = (float*)alloc(1024);      // sums[4][128] | sumsq[4][128]
    float* sst = (float*)alloc(4 * 256);     // per layer: scale[0..99], shift[128..227]
    int2* ew = (int2*)alloc(2 * (size_t)NEDGES);
    float* Abuf = (float*)alloc((size_t)NNODES * CH);
    float* Zbuf = (float*)alloc((size_t)NNODES * CH);
    float* gbuf = (float*)alloc((size_t)NGRAPH * CH);
    (void)ws_size; (void)n_in; (void)in_sizes; (void)out_size;

    hipLaunchKernelGGL(k_init, dim3((NNODES + 255) / 256), dim3(256), 0, stream, cnt, stats);
    hipLaunchKernelGGL(k_hist, dim3((NEDGES + 255) / 256), dim3(256), 0, stream, dstA, cnt);
    hipLaunchKernelGGL(k_dinv, dim3((NNODES + 255) / 256), dim3(256), 0, stream, cnt, dinv);
    hipLaunchKernelGGL(k_scan1, dim3(SCAN_BLOCKS), dim3(SCAN_TPB), 0, stream, cnt, rowptr, scanBlk);
    hipLaunchKernelGGL(k_scan2, dim3(1), dim3(64), 0, stream, scanBlk, scanOff);
    hipLaunchKernelGGL(k_scan3, dim3(SCAN_BLOCKS), dim3(SCAN_TPB), 0, stream, rowptr, cursor, scanOff);
    hipLaunchKernelGGL(k_scatter, dim3((NEDGES + 255) / 256), dim3(256), 0, stream,
                       srcA, dstA, dinv, cursor, ew);

    const float* Wl[4] = {W0, Wrest, Wrest + 10000, Wrest + 20000};
    for (int l = 0; l < 4; ++l) {
        if (l == 0) {
            hipLaunchKernelGGL((k_aggregate<CIN0, false>), dim3(12500), dim3(256), 0, stream,
                               x, Abuf, rowptr, ew, dinv, (const float*)nullptr);
            hipLaunchKernelGGL((k_gemm<CIN0, 40>), dim3((NNODES + 63) / 64), dim3(256), 0, stream,
                               Abuf, Wl[l], b + l * CH, Zbuf, stats + l * 128, stats + 512 + l * 128);
        } else {
            hipLaunchKernelGGL((k_aggregate<CH, true>), dim3(12500), dim3(256), 0, stream,
                               Zbuf, Abuf, rowptr, ew, dinv, sst + (l - 1) * 256);
            hipLaunchKernelGGL((k_gemm<CH, CH>), dim3((NNODES + 63) / 64), dim3(256), 0, stream,
                               Abuf, Wl[l], b + l * CH, Zbuf, stats + l * 128, stats + 512 + l * 128);
        }
        hipLaunchKernelGGL(k_finalize, dim3(1), dim3(128), 0, stream,
                           stats + l * 128, stats + 512 + l * 128, gamma + l * CH, beta + l * CH,
                           sst + l * 256);
    }
    hipLaunchKernelGGL(k_pool, dim3(NGRAPH), dim3(128), 0, stream, Zbuf, batch, sst + 3 * 256, gbuf);
    hipLaunchKernelGGL(k_out, dim3(NGRAPH), dim3(256), 0, stream, gbuf, Wout, bout, out);
}

// Round 4
// 734.811 us; speedup vs baseline: 1.0771x; 1.0771x over previous
//
#include <hip/hip_runtime.h>

#define NNODES 50000
#define NEDGES 800000
#define NGRAPH 500
#define CH 100
#define CIN0 33
#define BN_EPS 1e-5f

#define SCAN_TPB 256
#define SCAN_IPT 4
#define SCAN_TILE (SCAN_TPB * SCAN_IPT)
#define SCAN_BLOCKS ((NNODES + SCAN_TILE - 1) / SCAN_TILE)

// ---------------- init: zero histogram counters + BN stats + pool accumulator ----------------
__global__ void k_init(int* __restrict__ cnt, float* __restrict__ stats,
                       float* __restrict__ gbuf) {
    int i = blockIdx.x * blockDim.x + threadIdx.x;
    if (i < NNODES) cnt[i] = 0;
    if (i < NGRAPH * CH) gbuf[i] = 0.f;   // NGRAPH*CH == NNODES
    if (i < 1024) stats[i] = 0.f;
}

// ---------------- in-degree histogram over dst ----------------
__global__ void k_hist(const int* __restrict__ dst, int* __restrict__ cnt) {
    int e = blockIdx.x * blockDim.x + threadIdx.x;
    if (e < NEDGES) atomicAdd(&cnt[dst[e]], 1);
}

// ---------------- dinv = rsqrt(deg), deg = cnt + 1 (self loop) ----------------
__global__ void k_dinv(const int* __restrict__ cnt, float* __restrict__ dinv) {
    int i = blockIdx.x * blockDim.x + threadIdx.x;
    if (i < NNODES) dinv[i] = rsqrtf((float)(cnt[i] + 1));
}

// ---------------- exclusive scan of cnt -> rowptr (3 kernels) ----------------
__global__ void k_scan1(const int* __restrict__ cnt, int* __restrict__ rowptr,
                        int* __restrict__ blkSums) {
    __shared__ int ts[SCAN_TPB];
    int tid = threadIdx.x;
    int base = blockIdx.x * SCAN_TILE + tid * SCAN_IPT;
    int v[SCAN_IPT];
    int s = 0;
    #pragma unroll
    for (int j = 0; j < SCAN_IPT; ++j) {
        int i = base + j;
        v[j] = (i < NNODES) ? cnt[i] : 0;
        s += v[j];
    }
    ts[tid] = s;
    __syncthreads();
    for (int off = 1; off < SCAN_TPB; off <<= 1) {
        int add = (tid >= off) ? ts[tid - off] : 0;
        __syncthreads();
        ts[tid] += add;
        __syncthreads();
    }
    int run = ts[tid] - s;  // exclusive prefix within block
    #pragma unroll
    for (int j = 0; j < SCAN_IPT; ++j) {
        int i = base + j;
        if (i < NNODES) rowptr[i] = run;
        run += v[j];
    }
    if (tid == SCAN_TPB - 1) blkSums[blockIdx.x] = ts[tid];
}

__global__ void k_scan2(const int* __restrict__ blkSums, int* __restrict__ blkOff) {
    if (threadIdx.x == 0) {
        int run = 0;
        for (int i = 0; i < SCAN_BLOCKS; ++i) { blkOff[i] = run; run += blkSums[i]; }
    }
}

__global__ void k_scan3(int* __restrict__ rowptr, int* __restrict__ cursor,
                        const int* __restrict__ blkOff) {
    int off = blkOff[blockIdx.x];
    int base = blockIdx.x * SCAN_TILE + threadIdx.x * SCAN_IPT;
    #pragma unroll
    for (int j = 0; j < SCAN_IPT; ++j) {
        int i = base + j;
        if (i < NNODES) {
            int vv = rowptr[i] + off;
            rowptr[i] = vv;
            cursor[i] = vv;
        }
    }
    if (blockIdx.x == 0 && threadIdx.x == 0) rowptr[NNODES] = NEDGES;
}

// ---------------- scatter edges into CSR (by dst); pack (src, dinv[src]) ----------------
__global__ void k_scatter(const int* __restrict__ src, const int* __restrict__ dst,
                          const float* __restrict__ dinv, int* __restrict__ cursor,
                          int2* __restrict__ ew) {
    int e = blockIdx.x * blockDim.x + threadIdx.x;
    if (e < NEDGES) {
        int d = dst[e], s = src[e];
        int pos = atomicAdd(&cursor[d], 1);
        ew[pos] = make_int2(s, __float_as_int(dinv[s]));
    }
}

// ---------------- aggregate with optional fused BN(+ReLU) on gathered rows ----------------
// a[i] = dinv[i]*( sum_e dinv[src]*f(h[src]) + dinv[i]*f(h[i]) ),
// f(v) = BN ? relu(v*scale+shift) : v. One wave per node; 64 edge descriptors
// loaded coalesced and broadcast via shfl; row gathers unrolled 8x.
template<int C, bool BN>
__global__ __launch_bounds__(256) void k_aggregate(
    const float* __restrict__ h, float* __restrict__ a, const int* __restrict__ rowptr,
    const int2* __restrict__ ew, const float* __restrict__ dinv,
    const float* __restrict__ sst) {
    int node = (blockIdx.x * 256 + threadIdx.x) >> 6;
    int lane = threadIdx.x & 63;
    if (node >= NNODES) return;
    int p0 = rowptr[node], p1 = rowptr[node + 1];
    float di = dinv[node];

    if constexpr ((C & 1) == 0) {
        constexpr int HALF = C / 2;            // 50 for C=100
        bool act = lane < HALF;
        float scx = 0.f, scy = 0.f, shx = 0.f, shy = 0.f;
        if (BN && act) {
            float2 sc2 = ((const float2*)sst)[lane];
            float2 sh2 = ((const float2*)(sst + 128))[lane];
            scx = sc2.x; scy = sc2.y; shx = sh2.x; shy = sh2.y;
        }
        float ax = 0.f, ay = 0.f;
        for (int base = p0; base < p1; base += 64) {
            int nn = p1 - base; if (nn > 64) nn = 64;
            int2 e = make_int2(0, 0);
            if (lane < nn) e = ew[base + lane];
            int myc = e.x; float myw = __int_as_float(e.y);
            int j = 0;
            for (; j + 8 <= nn; j += 8) {
                int s[8]; float w[8];
                #pragma unroll
                for (int t = 0; t < 8; ++t) { s[t] = __shfl(myc, j + t); w[t] = __shfl(myw, j + t); }
                if (act) {
                    float2 v[8];
                    #pragma unroll
                    for (int t = 0; t < 8; ++t) v[t] = ((const float2*)(h + (size_t)s[t] * C))[lane];
                    #pragma unroll
                    for (int t = 0; t < 8; ++t) {
                        float vx = v[t].x, vy = v[t].y;
                        if (BN) {
                            vx = fmaxf(vx * scx + shx, 0.f);
                            vy = fmaxf(vy * scy + shy, 0.f);
                        }
                        ax += w[t] * vx; ay += w[t] * vy;
                    }
                }
            }
            for (; j < nn; ++j) {
                int s0 = __shfl(myc, j);
                float w0 = __shfl(myw, j);
                if (act) {
                    float2 v = ((const float2*)(h + (size_t)s0 * C))[lane];
                    float vx = v.x, vy = v.y;
                    if (BN) {
                        vx = fmaxf(vx * scx + shx, 0.f);
                        vy = fmaxf(vy * scy + shy, 0.f);
                    }
                    ax += w0 * vx; ay += w0 * vy;
                }
            }
        }
        if (act) {
            float2 hv = ((const float2*)(h + (size_t)node * C))[lane];
            float hx = hv.x, hy = hv.y;
            if (BN) {
                hx = fmaxf(hx * scx + shx, 0.f);
                hy = fmaxf(hy * scy + shy, 0.f);
            }
            float2 o;
            o.x = di * (ax + di * hx);
            o.y = di * (ay + di * hy);
            ((float2*)(a + (size_t)node * C))[lane] = o;
        }
    } else {
        bool m0 = lane < C;
        float sc = 0.f, sh = 0.f;
        if (BN && m0) { sc = sst[lane]; sh = sst[128 + lane]; }
        float acc0 = 0.f;
        for (int base = p0; base < p1; base += 64) {
            int nn = p1 - base; if (nn > 64) nn = 64;
            int2 e = make_int2(0, 0);
            if (lane < nn) e = ew[base + lane];
            int myc = e.x; float myw = __int_as_float(e.y);
            int j = 0;
            for (; j + 8 <= nn; j += 8) {
                int s[8]; float w[8];
                #pragma unroll
                for (int t = 0; t < 8; ++t) { s[t] = __shfl(myc, j + t); w[t] = __shfl(myw, j + t); }
                if (m0) {
                    float v[8];
                    #pragma unroll
                    for (int t = 0; t < 8; ++t) v[t] = h[(size_t)s[t] * C + lane];
                    #pragma unroll
                    for (int t = 0; t < 8; ++t) {
                        float vv = v[t];
                        if (BN) vv = fmaxf(vv * sc + sh, 0.f);
                        acc0 += w[t] * vv;
                    }
                }
            }
            for (; j < nn; ++j) {
                int s0 = __shfl(myc, j);
                float w0 = __shfl(myw, j);
                if (m0) {
                    float vv = h[(size_t)s0 * C + lane];
                    if (BN) vv = fmaxf(vv * sc + sh, 0.f);
                    acc0 += w0 * vv;
                }
            }
        }
        if (m0) {
            float hv = h[(size_t)node * C + lane];
            if (BN) hv = fmaxf(hv * sc + sh, 0.f);
            a[(size_t)node * C + lane] = di * (acc0 + di * hv);
        }
    }
}

// ---------------- Z = A @ W + bias ; fused per-channel sum/sumsq partials ----------------
// 64 rows x 100 cols per block. Only A staged in LDS (25.6 KB -> high occupancy);
// W read from global per k-step (broadcast across blocks -> L1/L2 resident).
// 200 threads: thread owns rows {rt, rt+8, ..., rt+56} (bank-safe: row delta 1 ->
// bank delta 4 across rt groups) and cols c0..c0+3. Single barrier.
template<int K, int KP>  // KP = K padded to multiple of 4 (LDS stride)
__global__ __launch_bounds__(256, 4) void k_gemm(
    const float* __restrict__ A, const float* __restrict__ W, const float* __restrict__ bias,
    float* __restrict__ Z, float* __restrict__ gsum, float* __restrict__ gsq) {
    __shared__ __align__(16) float aS[64 * KP];
    __shared__ float sSum[CH], sSq[CH];
    int tid = threadIdx.x;
    for (int i = tid; i < CH; i += 256) { sSum[i] = 0.f; sSq[i] = 0.f; }
    int row0 = blockIdx.x * 64;
    for (int i = tid; i < 64 * KP; i += 256) {
        int r = i / KP, kk = i % KP;
        int row = row0 + r;
        aS[i] = (row < NNODES && kk < K) ? A[(size_t)row * K + kk] : 0.f;
    }
    __syncthreads();
    if (tid < 200) {
        int ct = tid % 25, rt = tid / 25;  // ct 0..24, rt 0..7
        int c0 = ct * 4;
        float acc[8][4] = {};
        for (int k = 0; k < KP; k += 4) {
            float4 w0 = (k + 0 < K) ? *(const float4*)&W[(k + 0) * CH + c0] : make_float4(0, 0, 0, 0);
            float4 w1 = (k + 1 < K) ? *(const float4*)&W[(k + 1) * CH + c0] : make_float4(0, 0, 0, 0);
            float4 w2 = (k + 2 < K) ? *(const float4*)&W[(k + 2) * CH + c0] : make_float4(0, 0, 0, 0);
            float4 w3 = (k + 3 < K) ? *(const float4*)&W[(k + 3) * CH + c0] : make_float4(0, 0, 0, 0);
            #pragma unroll
            for (int j = 0; j < 8; ++j) {
                float4 av = *(const float4*)&aS[(rt + 8 * j) * KP + k];
                acc[j][0] += av.x * w0.x + av.y * w1.x + av.z * w2.x + av.w * w3.x;
                acc[j][1] += av.x * w0.y + av.y * w1.y + av.z * w2.y + av.w * w3.y;
                acc[j][2] += av.x * w0.z + av.y * w1.z + av.z * w2.z + av.w * w3.z;
                acc[j][3] += av.x * w0.w + av.y * w1.w + av.z * w2.w + av.w * w3.w;
            }
        }
        float b0 = bias[c0], b1 = bias[c0 + 1], b2 = bias[c0 + 2], b3 = bias[c0 + 3];
        float cs0 = 0, cs1 = 0, cs2 = 0, cs3 = 0, cq0 = 0, cq1 = 0, cq2 = 0, cq3 = 0;
        #pragma unroll
        for (int j = 0; j < 8; ++j) {
            int r = row0 + rt + 8 * j;
            if (r < NNODES) {
                float z0 = acc[j][0] + b0, z1 = acc[j][1] + b1;
                float z2 = acc[j][2] + b2, z3 = acc[j][3] + b3;
                *reinterpret_cast<float4*>(&Z[(size_t)r * CH + c0]) = make_float4(z0, z1, z2, z3);
                cs0 += z0; cs1 += z1; cs2 += z2; cs3 += z3;
                cq0 += z0 * z0; cq1 += z1 * z1; cq2 += z2 * z2; cq3 += z3 * z3;
            }
        }
        atomicAdd(&sSum[c0], cs0); atomicAdd(&sSum[c0 + 1], cs1);
        atomicAdd(&sSum[c0 + 2], cs2); atomicAdd(&sSum[c0 + 3], cs3);
        atomicAdd(&sSq[c0], cq0); atomicAdd(&sSq[c0 + 1], cq1);
        atomicAdd(&sSq[c0 + 2], cq2); atomicAdd(&sSq[c0 + 3], cq3);
    }
    __syncthreads();
    if (tid < CH) { atomicAdd(&gsum[tid], sSum[tid]); atomicAdd(&gsq[tid], sSq[tid]); }
}

// ---------------- BN finalize: scale/shift per channel ----------------
__global__ void k_finalize(const float* __restrict__ gsum, const float* __restrict__ gsq,
                           const float* __restrict__ gamma, const float* __restrict__ beta,
                           float* __restrict__ sst) {
    int c = threadIdx.x;
    if (c < CH) {
        float mean = gsum[c] * (1.f / NNODES);
        float var = gsq[c] * (1.f / NNODES) - mean * mean;
        float sc = gamma[c] * rsqrtf(var + BN_EPS);
        sst[c] = sc;
        sst[128 + c] = beta[c] - mean * sc;
    }
}

// ---------------- global_add_pool of BN(z) (no relu); 4 row-chunks per graph ----------------
__global__ void k_pool(const float* __restrict__ Zl, const int* __restrict__ batch,
                       const float* __restrict__ sst, float* __restrict__ g) {
    int gid = blockIdx.x;
    int part = blockIdx.y;
    int lo = 0, hi = NNODES;
    while (lo < hi) { int mid = (lo + hi) >> 1; if (batch[mid] < gid) lo = mid + 1; else hi = mid; }
    int start = lo;
    hi = NNODES;
    while (lo < hi) { int mid = (lo + hi) >> 1; if (batch[mid] < gid + 1) lo = mid + 1; else hi = mid; }
    int end = lo;
    int len = end - start;
    int cb = (len + 3) >> 2;
    int s = start + part * cb;
    int e = s + cb; if (e > end) e = end;
    if (s >= e) return;
    int c = threadIdx.x;
    if (c >= CH) return;
    float sc = sst[c], sh = sst[128 + c];
    float acc = 0.f;
    for (int r = s; r < e; ++r) acc += Zl[(size_t)r * CH + c];
    atomicAdd(&g[gid * CH + c], acc * sc + (float)(e - s) * sh);
}

// ---------------- out = leakyrelu(g @ Wout + bout, 0.1) ----------------
__global__ __launch_bounds__(256) void k_out(const float* __restrict__ g,
                                             const float* __restrict__ Wout,
                                             const float* __restrict__ bout,
                                             float* __restrict__ out) {
    __shared__ float gS[CH];
    int gid = blockIdx.x, tid = threadIdx.x;
    if (tid < CH) gS[tid] = g[gid * CH + tid];
    __syncthreads();
    if (tid >= 200) return;
    float acc = bout[tid];
    for (int k = 0; k < CH; ++k) acc += gS[k] * Wout[k * 200 + tid];
    out[gid * 200 + tid] = acc > 0.f ? acc : 0.1f * acc;
}

extern "C" void kernel_launch(void* const* d_in, const int* in_sizes, int n_in,
                              void* d_out, int out_size, void* d_ws, size_t ws_size,
                              hipStream_t stream) {
    const float* x = (const float*)d_in[0];
    const int* ei = (const int*)d_in[1];
    const int* batch = (const int*)d_in[2];
    const float* W0 = (const float*)d_in[3];
    const float* Wrest = (const float*)d_in[4];
    const float* b = (const float*)d_in[5];
    const float* gamma = (const float*)d_in[6];
    const float* beta = (const float*)d_in[7];
    const float* Wout = (const float*)d_in[8];
    const float* bout = (const float*)d_in[9];
    float* out = (float*)d_out;
    const int* srcA = ei;
    const int* dstA = ei + NEDGES;

    char* wsb = (char*)d_ws;
    size_t off = 0;
    auto alloc = [&](size_t elems) -> void* {
        void* p = (void*)(wsb + off);
        off += ((elems + 7) & ~(size_t)7) * 4;
        return p;
    };
    int* cnt = (int*)alloc(NNODES);
    int* rowptr = (int*)alloc(NNODES + 1);
    int* cursor = (int*)alloc(NNODES);
    float* dinv = (float*)alloc(NNODES);
    int* scanBlk = (int*)alloc(64);
    int* scanOff = (int*)alloc(64);
    float* stats = (float*)alloc(1024);      // sums[4][128] | sumsq[4][128]
    float* sst = (float*)alloc(4 * 256);     // per layer: scale[0..99], shift[128..227]
    int2* ew = (int2*)alloc(2 * (size_t)NEDGES);
    float* Abuf = (float*)alloc((size_t)NNODES * CH);
    float* Zbuf = (float*)alloc((size_t)NNODES * CH);
    float* gbuf = (float*)alloc((size_t)NGRAPH * CH);
    (void)ws_size; (void)n_in; (void)in_sizes; (void)out_size;

    hipLaunchKernelGGL(k_init, dim3((NNODES + 255) / 256), dim3(256), 0, stream, cnt, stats, gbuf);
    hipLaunchKernelGGL(k_hist, dim3((NEDGES + 255) / 256), dim3(256), 0, stream, dstA, cnt);
    hipLaunchKernelGGL(k_dinv, dim3((NNODES + 255) / 256), dim3(256), 0, stream, cnt, dinv);
    hipLaunchKernelGGL(k_scan1, dim3(SCAN_BLOCKS), dim3(SCAN_TPB), 0, stream, cnt, rowptr, scanBlk);
    hipLaunchKernelGGL(k_scan2, dim3(1), dim3(64), 0, stream, scanBlk, scanOff);
    hipLaunchKernelGGL(k_scan3, dim3(SCAN_BLOCKS), dim3(SCAN_TPB), 0, stream, rowptr, cursor, scanOff);
    hipLaunchKernelGGL(k_scatter, dim3((NEDGES + 255) / 256), dim3(256), 0, stream,
                       srcA, dstA, dinv, cursor, ew);

    const float* Wl[4] = {W0, Wrest, Wrest + 10000, Wrest + 20000};
    for (int l = 0; l < 4; ++l) {
        if (l == 0) {
            hipLaunchKernelGGL((k_aggregate<CIN0, false>), dim3(12500), dim3(256), 0, stream,
                               x, Abuf, rowptr, ew, dinv, (const float*)nullptr);
            hipLaunchKernelGGL((k_gemm<CIN0, 36>), dim3((NNODES + 63) / 64), dim3(256), 0, stream,
                               Abuf, Wl[l], b + l * CH, Zbuf, stats + l * 128, stats + 512 + l * 128);
        } else {
            hipLaunchKernelGGL((k_aggregate<CH, true>), dim3(12500), dim3(256), 0, stream,
                               Zbuf, Abuf, rowptr, ew, dinv, sst + (l - 1) * 256);
            hipLaunchKernelGGL((k_gemm<CH, CH>), dim3((NNODES + 63) / 64), dim3(256), 0, stream,
                               Abuf, Wl[l], b + l * CH, Zbuf, stats + l * 128, stats + 512 + l * 128);
        }
        hipLaunchKernelGGL(k_finalize, dim3(1), dim3(128), 0, stream,
                           stats + l * 128, stats + 512 + l * 128, gamma + l * CH, beta + l * CH,
                           sst + l * 256);
    }
    hipLaunchKernelGGL(k_pool, dim3(NGRAPH, 4), dim3(128), 0, stream, Zbuf, batch, sst + 3 * 256, gbuf);
    hipLaunchKernelGGL(k_out, dim3(NGRAPH), dim3(256), 0, stream, gbuf, Wout, bout, out);
}